// Round 1
// baseline (5360.436 us; speedup 1.0000x reference)
//
#include <hip/hip_runtime.h>
#include <hip/hip_bf16.h>
#include <cstddef>

#define THREADS 256

// ---------------- small kernels ----------------

__global__ void local_means_kernel(const float* __restrict__ lx,
                                   const int* __restrict__ lt,
                                   float* __restrict__ means, int nl)
{
    int tid = threadIdx.x;
    if (tid >= 7 * 19) return;
    int c = tid / 19, dd = tid % 19;
    float s = 0.f; int cnt = 0;
    for (int i = 0; i < nl; ++i) {
        if (lt[i] == c) { s += lx[i * 19 + dd]; cnt++; }
    }
    means[tid] = cnt > 0 ? s / (float)cnt : 0.f;
}

__global__ void deg_kernel(const int* __restrict__ dst, float* __restrict__ deg, int E)
{
    int t = blockIdx.x * THREADS + threadIdx.x;
    if (t < E) atomicAdd(&deg[dst[t]], 1.0f);
}

__global__ void dinv_kernel(float* __restrict__ deg, int n)
{
    int t = blockIdx.x * THREADS + threadIdx.x;
    if (t < n) deg[t] = rsqrtf(deg[t] + 1.0f);   // +1 self-loop; deg>=1 so max() moot
}

__global__ void build_x0_kernel(const float* __restrict__ means,
                                const int* __restrict__ vt,
                                const float* __restrict__ vx,
                                const float* __restrict__ label,
                                float* __restrict__ out, int n)
{
    int tid = blockIdx.x * THREADS + threadIdx.x;
    int node = tid >> 5, c = tid & 31;
    if (node >= n) return;
    float v;
    if (c < 19)      v = means[vt[node] * 19 + c];
    else if (c < 25) v = vx[node * 6 + (c - 19)];
    else             v = label[node * 7 + (c - 25)];
    out[(size_t)node * 32 + c] = v;
}

// ---------------- dense layer (x @ W [+b] [relu]), optional fused
// input transform y = relu(a*x + c) (GraphNorm+ReLU of previous layer) ----------------

template<int DIN, int DOUT, bool RELU, bool BIAS, bool TRANSFORM>
__global__ __launch_bounds__(256) void mlp_kernel(
    const float* __restrict__ in, float* __restrict__ out,
    const float* __restrict__ W, const float* __restrict__ bias,
    const float* __restrict__ tr /* a[0:DIN), c[DIN:2*DIN) */)
{
    constexpr int BN  = 64;   // nodes per block (n % 64 == 0 for this problem)
    constexpr int KT  = 32;   // k tile
    constexpr int BNP = 68;   // padded LDS stride (68*4B=272B, 16B-aligned, bank-spread)
    constexpr int TJ  = DOUT / 4;   // threads along j
    constexpr int TN  = 256 / TJ;   // threads along nodes
    constexpr int NPT = BN / TN;    // nodes per thread

    __shared__ float Wt[KT * DOUT];
    __shared__ float xT[KT][BNP];

    const int tid   = threadIdx.x;
    const int nbase = blockIdx.x * BN;
    const int tj = tid % TJ, tn = tid / TJ;
    const int j0 = tj * 4, n0 = tn * NPT;

    float acc[NPT][4];
#pragma unroll
    for (int p = 0; p < NPT; ++p) { acc[p][0] = acc[p][1] = acc[p][2] = acc[p][3] = 0.f; }

    for (int kt = 0; kt < DIN; kt += KT) {
        __syncthreads();
        // stage W tile (contiguous rows kt..kt+KT of row-major [DIN][DOUT])
        for (int i = tid * 4; i < KT * DOUT; i += THREADS * 4) {
            *(float4*)&Wt[i] = *(const float4*)&W[(size_t)kt * DOUT + i];
        }
        // stage x tile, transposed: xT[k][node]
        for (int i = tid; i < BN * (KT / 4); i += THREADS) {
            int node = i / (KT / 4);
            int kq   = i % (KT / 4);
            float4 v = *(const float4*)&in[(size_t)(nbase + node) * DIN + kt + kq * 4];
            if (TRANSFORM) {
                const float4 a = *(const float4*)&tr[kt + kq * 4];
                const float4 c = *(const float4*)&tr[DIN + kt + kq * 4];
                v.x = fmaxf(fmaf(v.x, a.x, c.x), 0.f);
                v.y = fmaxf(fmaf(v.y, a.y, c.y), 0.f);
                v.z = fmaxf(fmaf(v.z, a.z, c.z), 0.f);
                v.w = fmaxf(fmaf(v.w, a.w, c.w), 0.f);
            }
            xT[kq * 4 + 0][node] = v.x;
            xT[kq * 4 + 1][node] = v.y;
            xT[kq * 4 + 2][node] = v.z;
            xT[kq * 4 + 3][node] = v.w;
        }
        __syncthreads();
#pragma unroll
        for (int kk = 0; kk < KT; ++kk) {
            const float4 wv = *(const float4*)&Wt[kk * DOUT + j0];
            float xv[NPT];
            if constexpr (NPT == 8) {
                float4 v0 = *(const float4*)&xT[kk][n0];
                float4 v1 = *(const float4*)&xT[kk][n0 + 4];
                xv[0] = v0.x; xv[1] = v0.y; xv[2] = v0.z; xv[3] = v0.w;
                xv[4] = v1.x; xv[5] = v1.y; xv[6] = v1.z; xv[7] = v1.w;
            } else if constexpr (NPT == 4) {
                float4 v0 = *(const float4*)&xT[kk][n0];
                xv[0] = v0.x; xv[1] = v0.y; xv[2] = v0.z; xv[3] = v0.w;
            } else if constexpr (NPT == 2) {
                float2 v0 = *(const float2*)&xT[kk][n0];
                xv[0] = v0.x; xv[1] = v0.y;
            } else {
                xv[0] = xT[kk][n0];
            }
#pragma unroll
            for (int p = 0; p < NPT; ++p) {
                acc[p][0] = fmaf(xv[p], wv.x, acc[p][0]);
                acc[p][1] = fmaf(xv[p], wv.y, acc[p][1]);
                acc[p][2] = fmaf(xv[p], wv.z, acc[p][2]);
                acc[p][3] = fmaf(xv[p], wv.w, acc[p][3]);
            }
        }
    }

    float4 bv = make_float4(0.f, 0.f, 0.f, 0.f);
    if (BIAS) bv = *(const float4*)&bias[j0];
#pragma unroll
    for (int p = 0; p < NPT; ++p) {
        float4 o;
        o.x = acc[p][0] + bv.x;
        o.y = acc[p][1] + bv.y;
        o.z = acc[p][2] + bv.z;
        o.w = acc[p][3] + bv.w;
        if (RELU) {
            o.x = fmaxf(o.x, 0.f); o.y = fmaxf(o.y, 0.f);
            o.z = fmaxf(o.z, 0.f); o.w = fmaxf(o.w, 0.f);
        }
        *(float4*)&out[(size_t)(nbase + n0 + p) * DOUT + j0] = o;
    }
}

// ---------------- GCN aggregation ----------------
// agg = bias + xw * dinv^2   (self-loop term; also serves as the zero-init)
template<int D>
__global__ void scatter_init_kernel(const float* __restrict__ xw, float* __restrict__ agg,
                                    const float* __restrict__ dinv,
                                    const float* __restrict__ bias, int n)
{
    constexpr int JQ = D / 4;
    int tid = blockIdx.x * THREADS + threadIdx.x;
    int node = tid / JQ, jq = tid % JQ;
    if (node >= n) return;
    float di = dinv[node];
    float coef = di * di;
    float4 v = *(const float4*)&xw[(size_t)node * D + jq * 4];
    float4 b = *(const float4*)&bias[jq * 4];
    float4 o;
    o.x = fmaf(v.x, coef, b.x);
    o.y = fmaf(v.y, coef, b.y);
    o.z = fmaf(v.z, coef, b.z);
    o.w = fmaf(v.w, coef, b.w);
    *(float4*)&agg[(size_t)node * D + jq * 4] = o;
}

template<int D>
__global__ void scatter_edge_kernel(const float* __restrict__ xw, float* __restrict__ agg,
                                    const int* __restrict__ src, const int* __restrict__ dst,
                                    const float* __restrict__ dinv, int E)
{
    constexpr int JQ = D / 4;
    int tid = blockIdx.x * THREADS + threadIdx.x;
    int e = tid / JQ, jq = tid % JQ;
    if (e >= E) return;
    int s = src[e], d = dst[e];
    float coef = dinv[s] * dinv[d];
    float4 v = *(const float4*)&xw[(size_t)s * D + jq * 4];
    float* dest = &agg[(size_t)d * D + jq * 4];
    atomicAdd(dest + 0, v.x * coef);
    atomicAdd(dest + 1, v.y * coef);
    atomicAdd(dest + 2, v.z * coef);
    atomicAdd(dest + 3, v.w * coef);
}

// ---------------- GraphNorm stats: per-column sum and sumsq ----------------
template<int D>
__global__ __launch_bounds__(256) void gn_stats_kernel(const float* __restrict__ x,
                                                       float* __restrict__ stats, int n)
{
    constexpr int TPC   = 256 / D;     // threads per column
    constexpr int CHUNK = 8192 / D;    // rows per block
    const int tid  = threadIdx.x;
    const int col  = tid % D;
    const int rsub = tid / D;
    const int base = blockIdx.x * CHUNK;
    float s = 0.f, s2 = 0.f;
#pragma unroll
    for (int i = 0; i < CHUNK / TPC; ++i) {   // = 32
        int r = base + rsub + i * TPC;
        if (r < n) {
            float v = x[(size_t)r * D + col];
            s += v;
            s2 = fmaf(v, v, s2);
        }
    }
    __shared__ float red[2][256];
    red[0][tid] = s; red[1][tid] = s2;
    __syncthreads();
#pragma unroll
    for (int off = 128; off >= D; off >>= 1) {
        if (tid < off) {
            red[0][tid] += red[0][tid + off];
            red[1][tid] += red[1][tid + off];
        }
        __syncthreads();
    }
    if (tid < D) {
        atomicAdd(&stats[col],     red[0][tid]);
        atomicAdd(&stats[D + col], red[1][tid]);
    }
}

// Turn (sum, sumsq) into the fused affine y = a*x + c  (GraphNorm; ReLU applied by consumer)
template<int D>
__global__ void gn_finalize_kernel(float* __restrict__ stats,
                                   const float* __restrict__ gw, const float* __restrict__ gb,
                                   const float* __restrict__ gm, float inv_n)
{
    int j = threadIdx.x;
    if (j >= D) return;
    float mean = stats[j] * inv_n;
    float ex2  = stats[D + j] * inv_n;
    float m    = gm[j];
    // var = E[(x - m*mean)^2] = E[x^2] - (2m - m^2)*mean^2
    float var  = ex2 - (2.f * m - m * m) * mean * mean;
    float a    = gw[j] * rsqrtf(var + 1e-5f);
    float c    = gb[j] - a * m * mean;
    stats[j]     = a;
    stats[D + j] = c;
}

// ---------------- final 16->1 + sigmoid ----------------
__global__ void final_kernel(const float* __restrict__ in, const float* __restrict__ W,
                             const float* __restrict__ b, float* __restrict__ out, int n)
{
    int t = blockIdx.x * THREADS + threadIdx.x;
    if (t >= n) return;
    float acc = b[0];
#pragma unroll
    for (int k = 0; k < 16; ++k) acc = fmaf(in[(size_t)t * 16 + k], W[k], acc);
    out[t] = 1.0f / (1.0f + expf(-acc));
}

// ---------------- launch ----------------

extern "C" void kernel_launch(void* const* d_in, const int* in_sizes, int n_in,
                              void* d_out, int out_size, void* d_ws, size_t ws_size,
                              hipStream_t stream)
{
    const float* local_x    = (const float*)d_in[0];
    const int*   local_type = (const int*)d_in[1];
    const float* voxel_x    = (const float*)d_in[2];
    const int*   voxel_type = (const int*)d_in[3];
    const int*   edge_index = (const int*)d_in[4];
    const float* label      = (const float*)d_in[5];
    const float* We1 = (const float*)d_in[6],  *be1 = (const float*)d_in[7];
    const float* We2 = (const float*)d_in[8],  *be2 = (const float*)d_in[9];
    const float *Wc[4], *bc[4], *gw[4], *gb[4], *gm[4];
    for (int i = 0; i < 4; ++i) {
        Wc[i] = (const float*)d_in[10 + i * 5];
        bc[i] = (const float*)d_in[11 + i * 5];
        gw[i] = (const float*)d_in[12 + i * 5];
        gb[i] = (const float*)d_in[13 + i * 5];
        gm[i] = (const float*)d_in[14 + i * 5];
    }
    const float* Wd0 = (const float*)d_in[30], *bd0 = (const float*)d_in[31];
    const float* Wd1 = (const float*)d_in[32], *bd1 = (const float*)d_in[33];
    const float* Wd2 = (const float*)d_in[34], *bd2 = (const float*)d_in[35];
    const float* Wd3 = (const float*)d_in[36], *bd3 = (const float*)d_in[37];

    const int n  = in_sizes[2] / 6;    // 200000 (divisible by 64)
    const int E  = in_sizes[4] / 2;    // 1200000
    const int nl = in_sizes[0] / 19;   // 400
    const int* src = edge_index;
    const int* dst = edge_index + E;

    // workspace layout (~257 MB):
    // [stats 4KB][means 4KB][dinv n*4][C n*64*4][A n*128*4][B n*128*4]
    char* w = (char*)d_ws;
    float* stats = (float*)w;                  // 4 layers x 256 floats (sum/sumsq -> a/c)
    float* means = (float*)(w + 4096);         // 7x19
    float* dinv  = (float*)(w + 8192);         // deg then rsqrt in place
    size_t off = 8192 + (((size_t)n * sizeof(float) + 255) & ~(size_t)255);
    float* C = (float*)(w + off);              // up to 64-wide activations
    float* A = C + (size_t)n * 64;             // up to 128-wide
    float* B = A + (size_t)n * 128;            // up to 128-wide

    const float inv_n = 1.0f / (float)n;
    auto cdiv = [](long long a, long long b) { return (int)((a + b - 1) / b); };

    hipMemsetAsync(stats, 0, 4 * 256 * sizeof(float), stream);
    hipMemsetAsync(dinv, 0, (size_t)n * sizeof(float), stream);

    local_means_kernel<<<1, 192, 0, stream>>>(local_x, local_type, means, nl);
    deg_kernel<<<cdiv(E, 256), 256, 0, stream>>>(dst, dinv, E);
    dinv_kernel<<<cdiv(n, 256), 256, 0, stream>>>(dinv, n);
    build_x0_kernel<<<cdiv((long long)n * 32, 256), 256, 0, stream>>>(means, voxel_type, voxel_x, label, C, n);

    const int gmlp = n / 64;

    // encoder
    mlp_kernel<32, 128, true, true, false><<<gmlp, 256, 0, stream>>>(C, A, We1, be1, nullptr);
    mlp_kernel<128, 128, true, true, false><<<gmlp, 256, 0, stream>>>(A, B, We2, be2, nullptr);

    // conv0: B(128) -> xw C(64) -> agg A(64)
    mlp_kernel<128, 64, false, false, false><<<gmlp, 256, 0, stream>>>(B, C, Wc[0], nullptr, nullptr);
    scatter_init_kernel<64><<<cdiv((long long)n * 16, 256), 256, 0, stream>>>(C, A, dinv, bc[0], n);
    scatter_edge_kernel<64><<<cdiv((long long)E * 16, 256), 256, 0, stream>>>(C, A, src, dst, dinv, E);
    gn_stats_kernel<64><<<cdiv(n, 128), 256, 0, stream>>>(A, stats + 0, n);
    gn_finalize_kernel<64><<<1, 64, 0, stream>>>(stats + 0, gw[0], gb[0], gm[0], inv_n);

    // conv1: A(64,+GN) -> xw C(32) -> agg B(32)
    mlp_kernel<64, 32, false, false, true><<<gmlp, 256, 0, stream>>>(A, C, Wc[1], nullptr, stats + 0);
    scatter_init_kernel<32><<<cdiv((long long)n * 8, 256), 256, 0, stream>>>(C, B, dinv, bc[1], n);
    scatter_edge_kernel<32><<<cdiv((long long)E * 8, 256), 256, 0, stream>>>(C, B, src, dst, dinv, E);
    gn_stats_kernel<32><<<cdiv(n, 256), 256, 0, stream>>>(B, stats + 256, n);
    gn_finalize_kernel<32><<<1, 32, 0, stream>>>(stats + 256, gw[1], gb[1], gm[1], inv_n);

    // conv2: B(32,+GN) -> xw C(64) -> agg A(64)
    mlp_kernel<32, 64, false, false, true><<<gmlp, 256, 0, stream>>>(B, C, Wc[2], nullptr, stats + 256);
    scatter_init_kernel<64><<<cdiv((long long)n * 16, 256), 256, 0, stream>>>(C, A, dinv, bc[2], n);
    scatter_edge_kernel<64><<<cdiv((long long)E * 16, 256), 256, 0, stream>>>(C, A, src, dst, dinv, E);
    gn_stats_kernel<64><<<cdiv(n, 128), 256, 0, stream>>>(A, stats + 512, n);
    gn_finalize_kernel<64><<<1, 64, 0, stream>>>(stats + 512, gw[2], gb[2], gm[2], inv_n);

    // conv3: A(64,+GN) -> xw B(128) -> agg A... A is input; agg -> A after mlp done
    mlp_kernel<64, 128, false, false, true><<<gmlp, 256, 0, stream>>>(A, B, Wc[3], nullptr, stats + 512);
    scatter_init_kernel<128><<<cdiv((long long)n * 32, 256), 256, 0, stream>>>(B, A, dinv, bc[3], n);
    scatter_edge_kernel<128><<<cdiv((long long)E * 32, 256), 256, 0, stream>>>(B, A, src, dst, dinv, E);
    gn_stats_kernel<128><<<cdiv(n, 64), 256, 0, stream>>>(A, stats + 768, n);
    gn_finalize_kernel<128><<<1, 128, 0, stream>>>(stats + 768, gw[3], gb[3], gm[3], inv_n);

    // decoder: A(128,+GN) -> B(64) -> C(32) -> A(16) -> out
    mlp_kernel<128, 64, true, true, true><<<gmlp, 256, 0, stream>>>(A, B, Wd0, bd0, stats + 768);
    mlp_kernel<64, 32, true, true, false><<<gmlp, 256, 0, stream>>>(B, C, Wd1, bd1, nullptr);
    mlp_kernel<32, 16, true, true, false><<<gmlp, 256, 0, stream>>>(C, A, Wd2, bd2, nullptr);
    final_kernel<<<cdiv(n, 256), 256, 0, stream>>>(A, Wd3, bd3, (float*)d_out, n);
}

// Round 3
// 2039.343 us; speedup vs baseline: 2.6285x; 2.6285x over previous
//
#include <hip/hip_runtime.h>
#include <hip/hip_bf16.h>
#include <cstddef>

#define THREADS 256

// ---------------- small kernels ----------------

__global__ void local_means_kernel(const float* __restrict__ lx,
                                   const int* __restrict__ lt,
                                   float* __restrict__ means, int nl)
{
    int tid = threadIdx.x;
    if (tid >= 7 * 19) return;
    int c = tid / 19, dd = tid % 19;
    float s = 0.f; int cnt = 0;
    for (int i = 0; i < nl; ++i) {
        if (lt[i] == c) { s += lx[i * 19 + dd]; cnt++; }
    }
    means[tid] = cnt > 0 ? s / (float)cnt : 0.f;
}

__global__ void hist_kernel(const int* __restrict__ dst, int* __restrict__ degi, int E)
{
    int t = blockIdx.x * THREADS + threadIdx.x;
    if (t < E) atomicAdd(&degi[dst[t]], 1);
}

// single-block exclusive scan over degi -> rowptr (and cursor copy)
__global__ __launch_bounds__(1024) void scan_kernel(const int* __restrict__ degi,
                                                    int* __restrict__ rowptr,
                                                    int* __restrict__ cursor, int n)
{
    __shared__ int s[1024];
    const int tid = threadIdx.x;
    const int seg = (n + 1023) >> 10;
    const int start = tid * seg;
    const int end   = min(start + seg, n);
    int local = 0;
    for (int i = start; i < end; ++i) local += degi[i];
    s[tid] = local;
    __syncthreads();
    for (int off = 1; off < 1024; off <<= 1) {
        int v = (tid >= off) ? s[tid - off] : 0;
        __syncthreads();
        s[tid] += v;
        __syncthreads();
    }
    int run = s[tid] - local;   // exclusive prefix
    for (int i = start; i < end; ++i) {
        rowptr[i] = run;
        cursor[i] = run;
        run += degi[i];
    }
    if (end == n) rowptr[n] = run;
}

__global__ void dinv_kernel(const int* __restrict__ rowptr, float* __restrict__ dinv, int n)
{
    int t = blockIdx.x * THREADS + threadIdx.x;
    if (t < n) dinv[t] = rsqrtf((float)(rowptr[t + 1] - rowptr[t]) + 1.0f);  // +1 self-loop
}

__global__ void fill_kernel(const int* __restrict__ src, const int* __restrict__ dst,
                            int* __restrict__ cursor, int* __restrict__ esrc, int E)
{
    int t = blockIdx.x * THREADS + threadIdx.x;
    if (t >= E) return;
    int s = src[t], d = dst[t];
    int pos = atomicAdd(&cursor[d], 1);
    esrc[pos] = s;
}

__global__ void build_x0_kernel(const float* __restrict__ means,
                                const int* __restrict__ vt,
                                const float* __restrict__ vx,
                                const float* __restrict__ label,
                                float* __restrict__ out, int n)
{
    int tid = blockIdx.x * THREADS + threadIdx.x;
    int node = tid >> 5, c = tid & 31;
    if (node >= n) return;
    float v;
    if (c < 19)      v = means[vt[node] * 19 + c];
    else if (c < 25) v = vx[node * 6 + (c - 19)];
    else             v = label[node * 7 + (c - 25)];
    out[(size_t)node * 32 + c] = v;
}

// ---------------- dense layer (x @ W [+b] [relu]), optional fused input transform
// y = relu(a*x + c) (GraphNorm+ReLU of previous layer), optional output row-scale
// (fused GCN symmetric normalization: out_row *= dinv[node]) ----------------

template<int DIN, int DOUT, bool RELU, bool BIAS, bool TRANSFORM, bool SCALE>
__global__ __launch_bounds__(256) void mlp_kernel(
    const float* __restrict__ in, float* __restrict__ out,
    const float* __restrict__ W, const float* __restrict__ bias,
    const float* __restrict__ tr /* a[0:DIN), c[DIN:2*DIN) */,
    const float* __restrict__ rowscale)
{
    constexpr int BN  = 64;   // nodes per block (n % 64 == 0 here)
    constexpr int KT  = 32;   // k tile
    constexpr int BNP = 68;   // padded LDS stride
    constexpr int TJ  = DOUT / 4;   // threads along j
    constexpr int TN  = 256 / TJ;   // threads along nodes
    constexpr int NPT = BN / TN;    // nodes per thread

    __shared__ float Wt[KT * DOUT];
    __shared__ float xT[KT][BNP];

    const int tid   = threadIdx.x;
    const int nbase = blockIdx.x * BN;
    const int tj = tid % TJ, tn = tid / TJ;
    const int j0 = tj * 4, n0 = tn * NPT;

    float acc[NPT][4];
#pragma unroll
    for (int p = 0; p < NPT; ++p) { acc[p][0] = acc[p][1] = acc[p][2] = acc[p][3] = 0.f; }

    for (int kt = 0; kt < DIN; kt += KT) {
        __syncthreads();
        for (int i = tid * 4; i < KT * DOUT; i += THREADS * 4) {
            *(float4*)&Wt[i] = *(const float4*)&W[(size_t)kt * DOUT + i];
        }
        for (int i = tid; i < BN * (KT / 4); i += THREADS) {
            int node = i / (KT / 4);
            int kq   = i % (KT / 4);
            float4 v = *(const float4*)&in[(size_t)(nbase + node) * DIN + kt + kq * 4];
            if (TRANSFORM) {
                const float4 a = *(const float4*)&tr[kt + kq * 4];
                const float4 c = *(const float4*)&tr[DIN + kt + kq * 4];
                v.x = fmaxf(fmaf(v.x, a.x, c.x), 0.f);
                v.y = fmaxf(fmaf(v.y, a.y, c.y), 0.f);
                v.z = fmaxf(fmaf(v.z, a.z, c.z), 0.f);
                v.w = fmaxf(fmaf(v.w, a.w, c.w), 0.f);
            }
            xT[kq * 4 + 0][node] = v.x;
            xT[kq * 4 + 1][node] = v.y;
            xT[kq * 4 + 2][node] = v.z;
            xT[kq * 4 + 3][node] = v.w;
        }
        __syncthreads();
#pragma unroll
        for (int kk = 0; kk < KT; ++kk) {
            const float4 wv = *(const float4*)&Wt[kk * DOUT + j0];
            float xv[NPT];
            if constexpr (NPT == 8) {
                float4 v0 = *(const float4*)&xT[kk][n0];
                float4 v1 = *(const float4*)&xT[kk][n0 + 4];
                xv[0] = v0.x; xv[1] = v0.y; xv[2] = v0.z; xv[3] = v0.w;
                xv[4] = v1.x; xv[5] = v1.y; xv[6] = v1.z; xv[7] = v1.w;
            } else if constexpr (NPT == 4) {
                float4 v0 = *(const float4*)&xT[kk][n0];
                xv[0] = v0.x; xv[1] = v0.y; xv[2] = v0.z; xv[3] = v0.w;
            } else if constexpr (NPT == 2) {
                float2 v0 = *(const float2*)&xT[kk][n0];
                xv[0] = v0.x; xv[1] = v0.y;
            } else {
                xv[0] = xT[kk][n0];
            }
#pragma unroll
            for (int p = 0; p < NPT; ++p) {
                acc[p][0] = fmaf(xv[p], wv.x, acc[p][0]);
                acc[p][1] = fmaf(xv[p], wv.y, acc[p][1]);
                acc[p][2] = fmaf(xv[p], wv.z, acc[p][2]);
                acc[p][3] = fmaf(xv[p], wv.w, acc[p][3]);
            }
        }
    }

    float4 bv = make_float4(0.f, 0.f, 0.f, 0.f);
    if (BIAS) bv = *(const float4*)&bias[j0];
#pragma unroll
    for (int p = 0; p < NPT; ++p) {
        float4 o;
        o.x = acc[p][0] + bv.x;
        o.y = acc[p][1] + bv.y;
        o.z = acc[p][2] + bv.z;
        o.w = acc[p][3] + bv.w;
        if (RELU) {
            o.x = fmaxf(o.x, 0.f); o.y = fmaxf(o.y, 0.f);
            o.z = fmaxf(o.z, 0.f); o.w = fmaxf(o.w, 0.f);
        }
        if (SCALE) {
            const float rs = rowscale[nbase + n0 + p];
            o.x *= rs; o.y *= rs; o.z *= rs; o.w *= rs;
        }
        *(float4*)&out[(size_t)(nbase + n0 + p) * DOUT + j0] = o;
    }
}

// ---------------- CSR gather aggregation, fused self-loop+bias and GraphNorm stats ----
// y rows are pre-scaled by dinv (fused into the preceding GEMM), so:
//   out[d] = bias + dinv[d] * (y[d] + sum_{e: dst=d} y[esrc[e]])
// stats[0:D) += column sums of out; stats[D:2D) += column sums of out^2
template<int D>
__global__ __launch_bounds__(256) void gather_agg_kernel(
    const float* __restrict__ y, float* __restrict__ out,
    const int* __restrict__ rowptr, const int* __restrict__ esrc,
    const float* __restrict__ dinv,
    const float* __restrict__ bias, float* __restrict__ stats, int n)
{
    constexpr int JQ  = D / 4;       // threads per node
    constexpr int NPB = 256 / JQ;    // nodes per block-pass
    const int tid  = threadIdx.x;
    const int jq   = tid % JQ;
    const int nsub = tid / JQ;
    const int j0   = jq * 4;
    const float4 bv = *(const float4*)&bias[j0];

    float s1[4] = {0.f, 0.f, 0.f, 0.f};
    float s2[4] = {0.f, 0.f, 0.f, 0.f};

    const int ntiles = (n + NPB - 1) / NPB;
    for (int tile = blockIdx.x; tile < ntiles; tile += gridDim.x) {
        const int node = tile * NPB + nsub;
        if (node < n) {
            const int rb = rowptr[node], re = rowptr[node + 1];
            const float dd = dinv[node];
            float4 acc = *(const float4*)&y[(size_t)node * D + j0];  // self term
            for (int k = rb; k < re; ++k) {
                const int s = esrc[k];
                const float4 v = *(const float4*)&y[(size_t)s * D + j0];
                acc.x += v.x; acc.y += v.y; acc.z += v.z; acc.w += v.w;
            }
            float4 o;
            o.x = fmaf(acc.x, dd, bv.x);
            o.y = fmaf(acc.y, dd, bv.y);
            o.z = fmaf(acc.z, dd, bv.z);
            o.w = fmaf(acc.w, dd, bv.w);
            *(float4*)&out[(size_t)node * D + j0] = o;
            s1[0] += o.x; s1[1] += o.y; s1[2] += o.z; s1[3] += o.w;
            s2[0] = fmaf(o.x, o.x, s2[0]);
            s2[1] = fmaf(o.y, o.y, s2[1]);
            s2[2] = fmaf(o.z, o.z, s2[2]);
            s2[3] = fmaf(o.w, o.w, s2[3]);
        }
    }

    // block-reduce stats across node groups (same jq, different nsub)
    __shared__ float red[256][8];
#pragma unroll
    for (int j = 0; j < 4; ++j) { red[tid][j] = s1[j]; red[tid][4 + j] = s2[j]; }
    __syncthreads();
#pragma unroll
    for (int off = NPB / 2; off >= 1; off >>= 1) {
        if (nsub < off) {
#pragma unroll
            for (int j = 0; j < 8; ++j) red[tid][j] += red[tid + off * JQ][j];
        }
        __syncthreads();
    }
    if (nsub == 0) {
#pragma unroll
        for (int j = 0; j < 4; ++j) {
            atomicAdd(&stats[j0 + j],     red[tid][j]);
            atomicAdd(&stats[D + j0 + j], red[tid][4 + j]);
        }
    }
}

// Turn (sum, sumsq) into the fused affine y = a*x + c  (GraphNorm; ReLU applied by consumer)
template<int D>
__global__ void gn_finalize_kernel(float* __restrict__ stats,
                                   const float* __restrict__ gw, const float* __restrict__ gb,
                                   const float* __restrict__ gm, float inv_n)
{
    int j = threadIdx.x;
    if (j >= D) return;
    float mean = stats[j] * inv_n;
    float ex2  = stats[D + j] * inv_n;
    float m    = gm[j];
    // var = E[(x - m*mean)^2] = E[x^2] - (2m - m^2)*mean^2
    float var  = ex2 - (2.f * m - m * m) * mean * mean;
    float a    = gw[j] * rsqrtf(var + 1e-5f);
    float c    = gb[j] - a * m * mean;
    stats[j]     = a;
    stats[D + j] = c;
}

// ---------------- final 16->1 + sigmoid ----------------
__global__ void final_kernel(const float* __restrict__ in, const float* __restrict__ W,
                             const float* __restrict__ b, float* __restrict__ out, int n)
{
    int t = blockIdx.x * THREADS + threadIdx.x;
    if (t >= n) return;
    float acc = b[0];
#pragma unroll
    for (int k = 0; k < 16; ++k) acc = fmaf(in[(size_t)t * 16 + k], W[k], acc);
    out[t] = 1.0f / (1.0f + expf(-acc));
}

// ---------------- launch ----------------

extern "C" void kernel_launch(void* const* d_in, const int* in_sizes, int n_in,
                              void* d_out, int out_size, void* d_ws, size_t ws_size,
                              hipStream_t stream)
{
    const float* local_x    = (const float*)d_in[0];
    const int*   local_type = (const int*)d_in[1];
    const float* voxel_x    = (const float*)d_in[2];
    const int*   voxel_type = (const int*)d_in[3];
    const int*   edge_index = (const int*)d_in[4];
    const float* label      = (const float*)d_in[5];
    const float* We1 = (const float*)d_in[6],  *be1 = (const float*)d_in[7];
    const float* We2 = (const float*)d_in[8],  *be2 = (const float*)d_in[9];
    const float *Wc[4], *bc[4], *gw[4], *gb[4], *gm[4];
    for (int i = 0; i < 4; ++i) {
        Wc[i] = (const float*)d_in[10 + i * 5];
        bc[i] = (const float*)d_in[11 + i * 5];
        gw[i] = (const float*)d_in[12 + i * 5];
        gb[i] = (const float*)d_in[13 + i * 5];
        gm[i] = (const float*)d_in[14 + i * 5];
    }
    const float* Wd0 = (const float*)d_in[30], *bd0 = (const float*)d_in[31];
    const float* Wd1 = (const float*)d_in[32], *bd1 = (const float*)d_in[33];
    const float* Wd2 = (const float*)d_in[34], *bd2 = (const float*)d_in[35];
    const float* Wd3 = (const float*)d_in[36], *bd3 = (const float*)d_in[37];

    const int n  = in_sizes[2] / 6;    // 200000
    const int E  = in_sizes[4] / 2;    // 1200000
    const int nl = in_sizes[0] / 19;   // 400
    const int* src = edge_index;
    const int* dst = edge_index + E;

    // Compact workspace (~211.2 MB, proven-safe < round-1's 257 MB):
    // [stats 4KB][means 4KB][rowptr n+1][dinv n][esrc E][A n*128][B n*128]
    // transient degi/cursor alias the A region (A first written at encoder-1,
    // strictly after CSR build completes; all kernels stream-ordered).
    auto align256 = [](size_t x) { return (x + 255) & ~(size_t)255; };
    char* w = (char*)d_ws;
    float* stats = (float*)w;                  // 4 layers x 256 floats (sum/sumsq -> a/c)
    float* means = (float*)(w + 4096);
    size_t off = 8192;
    int*   rowptr = (int*)(w + off);   off += align256((size_t)(n + 1) * 4);
    float* dinv   = (float*)(w + off); off += align256((size_t)n * 4);
    int*   esrc   = (int*)(w + off);   off += align256((size_t)E * 4);
    float* A  = (float*)(w + off);             // n*128 floats
    float* B  = A + (size_t)n * 128;           // n*128 floats
    float* A2 = A + (size_t)n * 64;            // second half of A (<=64-wide use)
    float* B2 = B + (size_t)n * 64;            // second half of B
    int*   degi   = (int*)A;                   // transient alias
    int*   cursor = (int*)A2;                  // transient alias

    const float inv_n = 1.0f / (float)n;
    auto cdiv = [](long long a, long long b) { return (int)((a + b - 1) / b); };

    hipMemsetAsync(stats, 0, 4 * 256 * sizeof(float), stream);
    hipMemsetAsync(degi, 0, (size_t)n * sizeof(int), stream);

    local_means_kernel<<<1, 192, 0, stream>>>(local_x, local_type, means, nl);
    hist_kernel<<<cdiv(E, 256), 256, 0, stream>>>(dst, degi, E);
    scan_kernel<<<1, 1024, 0, stream>>>(degi, rowptr, cursor, n);
    dinv_kernel<<<cdiv(n, 256), 256, 0, stream>>>(rowptr, dinv, n);
    fill_kernel<<<cdiv(E, 256), 256, 0, stream>>>(src, dst, cursor, esrc, E);
    build_x0_kernel<<<cdiv((long long)n * 32, 256), 256, 0, stream>>>(means, voxel_type, voxel_x, label, B, n);

    const int gmlp = n / 64;
    const int gagg = 2048;

    // encoder: B(32) -> A(128) -> B(128)
    mlp_kernel<32, 128, true, true, false, false><<<gmlp, 256, 0, stream>>>(B, A, We1, be1, nullptr, nullptr);
    mlp_kernel<128, 128, true, true, false, false><<<gmlp, 256, 0, stream>>>(A, B, We2, be2, nullptr, nullptr);

    // conv0: B(128) -> y A(64, dinv-scaled) -> agg A2(64) [+stats]
    mlp_kernel<128, 64, false, false, false, true><<<gmlp, 256, 0, stream>>>(B, A, Wc[0], nullptr, nullptr, dinv);
    gather_agg_kernel<64><<<gagg, 256, 0, stream>>>(A, A2, rowptr, esrc, dinv, bc[0], stats + 0, n);
    gn_finalize_kernel<64><<<1, 64, 0, stream>>>(stats + 0, gw[0], gb[0], gm[0], inv_n);

    // conv1: A2(64,+GN) -> y B(32) -> agg B2(32)
    mlp_kernel<64, 32, false, false, true, true><<<gmlp, 256, 0, stream>>>(A2, B, Wc[1], nullptr, stats + 0, dinv);
    gather_agg_kernel<32><<<gagg, 256, 0, stream>>>(B, B2, rowptr, esrc, dinv, bc[1], stats + 256, n);
    gn_finalize_kernel<32><<<1, 32, 0, stream>>>(stats + 256, gw[1], gb[1], gm[1], inv_n);

    // conv2: B2(32,+GN) -> y A(64) -> agg A2(64)
    mlp_kernel<32, 64, false, false, true, true><<<gmlp, 256, 0, stream>>>(B2, A, Wc[2], nullptr, stats + 256, dinv);
    gather_agg_kernel<64><<<gagg, 256, 0, stream>>>(A, A2, rowptr, esrc, dinv, bc[2], stats + 512, n);
    gn_finalize_kernel<64><<<1, 64, 0, stream>>>(stats + 512, gw[2], gb[2], gm[2], inv_n);

    // conv3: A2(64,+GN) -> y B(128) -> agg A(128)
    mlp_kernel<64, 128, false, false, true, true><<<gmlp, 256, 0, stream>>>(A2, B, Wc[3], nullptr, stats + 512, dinv);
    gather_agg_kernel<128><<<gagg, 256, 0, stream>>>(B, A, rowptr, esrc, dinv, bc[3], stats + 768, n);
    gn_finalize_kernel<128><<<1, 128, 0, stream>>>(stats + 768, gw[3], gb[3], gm[3], inv_n);

    // decoder: A(128,+GN) -> B(64) -> B2(32) -> A(16) -> out
    mlp_kernel<128, 64, true, true, true, false><<<gmlp, 256, 0, stream>>>(A, B, Wd0, bd0, stats + 768, nullptr);
    mlp_kernel<64, 32, true, true, false, false><<<gmlp, 256, 0, stream>>>(B, B2, Wd1, bd1, nullptr, nullptr);
    mlp_kernel<32, 16, true, true, false, false><<<gmlp, 256, 0, stream>>>(B2, A, Wd2, bd2, nullptr, nullptr);
    final_kernel<<<cdiv(n, 256), 256, 0, stream>>>(A, Wd3, bd3, (float*)d_out, n);
}

// Round 4
// 1607.734 us; speedup vs baseline: 3.3342x; 1.2685x over previous
//
#include <hip/hip_runtime.h>
#include <hip/hip_bf16.h>
#include <cstddef>

#define THREADS 256

// ---------------- small kernels ----------------

__global__ void local_means_kernel(const float* __restrict__ lx,
                                   const int* __restrict__ lt,
                                   float* __restrict__ means, int nl)
{
    int tid = threadIdx.x;
    if (tid >= 7 * 19) return;
    int c = tid / 19, dd = tid % 19;
    float s = 0.f; int cnt = 0;
    for (int i = 0; i < nl; ++i) {
        if (lt[i] == c) { s += lx[i * 19 + dd]; cnt++; }
    }
    means[tid] = cnt > 0 ? s / (float)cnt : 0.f;
}

__global__ void hist_kernel(const int* __restrict__ dst, int* __restrict__ degi, int E)
{
    int t = blockIdx.x * THREADS + threadIdx.x;
    if (t < E) atomicAdd(&degi[dst[t]], 1);
}

// ---- 3-pass parallel exclusive scan over degi (1024 elements per block) ----

__global__ __launch_bounds__(256) void scan_part1_kernel(const int* __restrict__ degi,
                                                         int* __restrict__ blocksums, int n)
{
    const int tid = threadIdx.x;
    const int idx = blockIdx.x * 1024 + tid * 4;
    int v = 0;
    if (idx + 3 < n) {
        int4 d = *(const int4*)&degi[idx];
        v = d.x + d.y + d.z + d.w;
    } else {
        for (int i = 0; i < 4; ++i) if (idx + i < n) v += degi[idx + i];
    }
    __shared__ int s[256];
    s[tid] = v;
    __syncthreads();
    for (int off = 128; off >= 1; off >>= 1) {
        if (tid < off) s[tid] += s[tid + off];
        __syncthreads();
    }
    if (tid == 0) blocksums[blockIdx.x] = s[0];
}

// single block; nb <= 256
__global__ __launch_bounds__(256) void scan_part2_kernel(int* __restrict__ blocksums, int nb)
{
    __shared__ int s[256];
    const int tid = threadIdx.x;
    int v = (tid < nb) ? blocksums[tid] : 0;
    s[tid] = v;
    __syncthreads();
    for (int off = 1; off < 256; off <<= 1) {
        int t = (tid >= off) ? s[tid - off] : 0;
        __syncthreads();
        s[tid] += t;
        __syncthreads();
    }
    if (tid < nb) blocksums[tid] = s[tid] - v;  // exclusive
}

__global__ __launch_bounds__(256) void scan_part3_kernel(const int* __restrict__ degi,
                                                         const int* __restrict__ blocksums,
                                                         int* __restrict__ rowptr,
                                                         int* __restrict__ cursor, int n, int E)
{
    const int tid = threadIdx.x;
    const int idx = blockIdx.x * 1024 + tid * 4;
    int d0 = 0, d1 = 0, d2 = 0, d3 = 0;
    if (idx + 3 < n) {
        int4 d = *(const int4*)&degi[idx];
        d0 = d.x; d1 = d.y; d2 = d.z; d3 = d.w;
    } else {
        if (idx     < n) d0 = degi[idx];
        if (idx + 1 < n) d1 = degi[idx + 1];
        if (idx + 2 < n) d2 = degi[idx + 2];
        if (idx + 3 < n) d3 = degi[idx + 3];
    }
    const int v = d0 + d1 + d2 + d3;
    __shared__ int s[256];
    s[tid] = v;
    __syncthreads();
    for (int off = 1; off < 256; off <<= 1) {
        int t = (tid >= off) ? s[tid - off] : 0;
        __syncthreads();
        s[tid] += t;
        __syncthreads();
    }
    int run = blocksums[blockIdx.x] + s[tid] - v;  // exclusive prefix for this thread
    if (idx + 3 < n) {
        int4 o;
        o.x = run; run += d0;
        o.y = run; run += d1;
        o.z = run; run += d2;
        o.w = run;
        *(int4*)&rowptr[idx] = o;
        *(int4*)&cursor[idx] = o;
    } else {
        if (idx     < n) { rowptr[idx]     = run; cursor[idx]     = run; run += d0; }
        if (idx + 1 < n) { rowptr[idx + 1] = run; cursor[idx + 1] = run; run += d1; }
        if (idx + 2 < n) { rowptr[idx + 2] = run; cursor[idx + 2] = run; run += d2; }
        if (idx + 3 < n) { rowptr[idx + 3] = run; cursor[idx + 3] = run; }
    }
    if (blockIdx.x == 0 && tid == 0) rowptr[n] = E;
}

__global__ void dinv_kernel(const int* __restrict__ rowptr, float* __restrict__ dinv, int n)
{
    int t = blockIdx.x * THREADS + threadIdx.x;
    if (t < n) dinv[t] = rsqrtf((float)(rowptr[t + 1] - rowptr[t]) + 1.0f);  // +1 self-loop
}

__global__ void fill_kernel(const int* __restrict__ src, const int* __restrict__ dst,
                            int* __restrict__ cursor, int* __restrict__ esrc, int E)
{
    int t = blockIdx.x * THREADS + threadIdx.x;
    if (t >= E) return;
    int s = src[t], d = dst[t];
    int pos = atomicAdd(&cursor[d], 1);
    esrc[pos] = s;
}

__global__ void build_x0_kernel(const float* __restrict__ means,
                                const int* __restrict__ vt,
                                const float* __restrict__ vx,
                                const float* __restrict__ label,
                                float* __restrict__ out, int n)
{
    int tid = blockIdx.x * THREADS + threadIdx.x;
    int node = tid >> 5, c = tid & 31;
    if (node >= n) return;
    float v;
    if (c < 19)      v = means[vt[node] * 19 + c];
    else if (c < 25) v = vx[node * 6 + (c - 19)];
    else             v = label[node * 7 + (c - 25)];
    out[(size_t)node * 32 + c] = v;
}

// ---------------- dense layer (x @ W [+b] [relu]), optional fused input transform
// y = relu(a*x + c) (GraphNorm+ReLU of previous layer), optional output row-scale
// (fused GCN symmetric normalization: out_row *= dinv[node]) ----------------

template<int DIN, int DOUT, bool RELU, bool BIAS, bool TRANSFORM, bool SCALE>
__global__ __launch_bounds__(256) void mlp_kernel(
    const float* __restrict__ in, float* __restrict__ out,
    const float* __restrict__ W, const float* __restrict__ bias,
    const float* __restrict__ tr /* a[0:DIN), c[DIN:2*DIN) */,
    const float* __restrict__ rowscale)
{
    constexpr int BN  = 64;   // nodes per block (n % 64 == 0 here)
    constexpr int KT  = 32;   // k tile
    constexpr int BNP = 68;   // padded LDS stride
    constexpr int TJ  = DOUT / 4;   // threads along j
    constexpr int TN  = 256 / TJ;   // threads along nodes
    constexpr int NPT = BN / TN;    // nodes per thread

    __shared__ float Wt[KT * DOUT];
    __shared__ float xT[KT][BNP];

    const int tid   = threadIdx.x;
    const int nbase = blockIdx.x * BN;
    const int tj = tid % TJ, tn = tid / TJ;
    const int j0 = tj * 4, n0 = tn * NPT;

    float acc[NPT][4];
#pragma unroll
    for (int p = 0; p < NPT; ++p) { acc[p][0] = acc[p][1] = acc[p][2] = acc[p][3] = 0.f; }

    for (int kt = 0; kt < DIN; kt += KT) {
        __syncthreads();
        for (int i = tid * 4; i < KT * DOUT; i += THREADS * 4) {
            *(float4*)&Wt[i] = *(const float4*)&W[(size_t)kt * DOUT + i];
        }
        for (int i = tid; i < BN * (KT / 4); i += THREADS) {
            int node = i / (KT / 4);
            int kq   = i % (KT / 4);
            float4 v = *(const float4*)&in[(size_t)(nbase + node) * DIN + kt + kq * 4];
            if (TRANSFORM) {
                const float4 a = *(const float4*)&tr[kt + kq * 4];
                const float4 c = *(const float4*)&tr[DIN + kt + kq * 4];
                v.x = fmaxf(fmaf(v.x, a.x, c.x), 0.f);
                v.y = fmaxf(fmaf(v.y, a.y, c.y), 0.f);
                v.z = fmaxf(fmaf(v.z, a.z, c.z), 0.f);
                v.w = fmaxf(fmaf(v.w, a.w, c.w), 0.f);
            }
            xT[kq * 4 + 0][node] = v.x;
            xT[kq * 4 + 1][node] = v.y;
            xT[kq * 4 + 2][node] = v.z;
            xT[kq * 4 + 3][node] = v.w;
        }
        __syncthreads();
#pragma unroll
        for (int kk = 0; kk < KT; ++kk) {
            const float4 wv = *(const float4*)&Wt[kk * DOUT + j0];
            float xv[NPT];
            if constexpr (NPT == 8) {
                float4 v0 = *(const float4*)&xT[kk][n0];
                float4 v1 = *(const float4*)&xT[kk][n0 + 4];
                xv[0] = v0.x; xv[1] = v0.y; xv[2] = v0.z; xv[3] = v0.w;
                xv[4] = v1.x; xv[5] = v1.y; xv[6] = v1.z; xv[7] = v1.w;
            } else if constexpr (NPT == 4) {
                float4 v0 = *(const float4*)&xT[kk][n0];
                xv[0] = v0.x; xv[1] = v0.y; xv[2] = v0.z; xv[3] = v0.w;
            } else if constexpr (NPT == 2) {
                float2 v0 = *(const float2*)&xT[kk][n0];
                xv[0] = v0.x; xv[1] = v0.y;
            } else {
                xv[0] = xT[kk][n0];
            }
#pragma unroll
            for (int p = 0; p < NPT; ++p) {
                acc[p][0] = fmaf(xv[p], wv.x, acc[p][0]);
                acc[p][1] = fmaf(xv[p], wv.y, acc[p][1]);
                acc[p][2] = fmaf(xv[p], wv.z, acc[p][2]);
                acc[p][3] = fmaf(xv[p], wv.w, acc[p][3]);
            }
        }
    }

    float4 bv = make_float4(0.f, 0.f, 0.f, 0.f);
    if (BIAS) bv = *(const float4*)&bias[j0];
#pragma unroll
    for (int p = 0; p < NPT; ++p) {
        float4 o;
        o.x = acc[p][0] + bv.x;
        o.y = acc[p][1] + bv.y;
        o.z = acc[p][2] + bv.z;
        o.w = acc[p][3] + bv.w;
        if (RELU) {
            o.x = fmaxf(o.x, 0.f); o.y = fmaxf(o.y, 0.f);
            o.z = fmaxf(o.z, 0.f); o.w = fmaxf(o.w, 0.f);
        }
        if (SCALE) {
            const float rs = rowscale[nbase + n0 + p];
            o.x *= rs; o.y *= rs; o.z *= rs; o.w *= rs;
        }
        *(float4*)&out[(size_t)(nbase + n0 + p) * DOUT + j0] = o;
    }
}

// ---------------- CSR gather aggregation, fused self-loop+bias and GraphNorm stats ----
// y rows are pre-scaled by dinv (fused into the preceding GEMM), so:
//   out[d] = bias + dinv[d] * (y[d] + sum_{e: dst=d} y[esrc[e]])
// stats[0:D) += column sums of out; stats[D:2D) += column sums of out^2
template<int D>
__global__ __launch_bounds__(256) void gather_agg_kernel(
    const float* __restrict__ y, float* __restrict__ out,
    const int* __restrict__ rowptr, const int* __restrict__ esrc,
    const float* __restrict__ dinv,
    const float* __restrict__ bias, float* __restrict__ stats, int n)
{
    constexpr int JQ  = D / 4;       // threads per node
    constexpr int NPB = 256 / JQ;    // nodes per block-pass
    const int tid  = threadIdx.x;
    const int jq   = tid % JQ;
    const int nsub = tid / JQ;
    const int j0   = jq * 4;
    const float4 bv = *(const float4*)&bias[j0];

    float s1[4] = {0.f, 0.f, 0.f, 0.f};
    float s2[4] = {0.f, 0.f, 0.f, 0.f};

    const int ntiles = (n + NPB - 1) / NPB;
    for (int tile = blockIdx.x; tile < ntiles; tile += gridDim.x) {
        const int node = tile * NPB + nsub;
        if (node < n) {
            const int rb = rowptr[node], re = rowptr[node + 1];
            const float dd = dinv[node];
            float4 acc = *(const float4*)&y[(size_t)node * D + j0];  // self term
            for (int k = rb; k < re; ++k) {
                const int s = esrc[k];
                const float4 v = *(const float4*)&y[(size_t)s * D + j0];
                acc.x += v.x; acc.y += v.y; acc.z += v.z; acc.w += v.w;
            }
            float4 o;
            o.x = fmaf(acc.x, dd, bv.x);
            o.y = fmaf(acc.y, dd, bv.y);
            o.z = fmaf(acc.z, dd, bv.z);
            o.w = fmaf(acc.w, dd, bv.w);
            *(float4*)&out[(size_t)node * D + j0] = o;
            s1[0] += o.x; s1[1] += o.y; s1[2] += o.z; s1[3] += o.w;
            s2[0] = fmaf(o.x, o.x, s2[0]);
            s2[1] = fmaf(o.y, o.y, s2[1]);
            s2[2] = fmaf(o.z, o.z, s2[2]);
            s2[3] = fmaf(o.w, o.w, s2[3]);
        }
    }

    // block-reduce stats across node groups (same jq, different nsub)
    __shared__ float red[256][8];
#pragma unroll
    for (int j = 0; j < 4; ++j) { red[tid][j] = s1[j]; red[tid][4 + j] = s2[j]; }
    __syncthreads();
#pragma unroll
    for (int off = NPB / 2; off >= 1; off >>= 1) {
        if (nsub < off) {
#pragma unroll
            for (int j = 0; j < 8; ++j) red[tid][j] += red[tid + off * JQ][j];
        }
        __syncthreads();
    }
    if (nsub == 0) {
#pragma unroll
        for (int j = 0; j < 4; ++j) {
            atomicAdd(&stats[j0 + j],     red[tid][j]);
            atomicAdd(&stats[D + j0 + j], red[tid][4 + j]);
        }
    }
}

// Turn (sum, sumsq) into the fused affine y = a*x + c  (GraphNorm; ReLU applied by consumer)
template<int D>
__global__ void gn_finalize_kernel(float* __restrict__ stats,
                                   const float* __restrict__ gw, const float* __restrict__ gb,
                                   const float* __restrict__ gm, float inv_n)
{
    int j = threadIdx.x;
    if (j >= D) return;
    float mean = stats[j] * inv_n;
    float ex2  = stats[D + j] * inv_n;
    float m    = gm[j];
    // var = E[(x - m*mean)^2] = E[x^2] - (2m - m^2)*mean^2
    float var  = ex2 - (2.f * m - m * m) * mean * mean;
    float a    = gw[j] * rsqrtf(var + 1e-5f);
    float c    = gb[j] - a * m * mean;
    stats[j]     = a;
    stats[D + j] = c;
}

// ---------------- final 16->1 + sigmoid ----------------
__global__ void final_kernel(const float* __restrict__ in, const float* __restrict__ W,
                             const float* __restrict__ b, float* __restrict__ out, int n)
{
    int t = blockIdx.x * THREADS + threadIdx.x;
    if (t >= n) return;
    float acc = b[0];
#pragma unroll
    for (int k = 0; k < 16; ++k) acc = fmaf(in[(size_t)t * 16 + k], W[k], acc);
    out[t] = 1.0f / (1.0f + expf(-acc));
}

// ---------------- launch ----------------

extern "C" void kernel_launch(void* const* d_in, const int* in_sizes, int n_in,
                              void* d_out, int out_size, void* d_ws, size_t ws_size,
                              hipStream_t stream)
{
    const float* local_x    = (const float*)d_in[0];
    const int*   local_type = (const int*)d_in[1];
    const float* voxel_x    = (const float*)d_in[2];
    const int*   voxel_type = (const int*)d_in[3];
    const int*   edge_index = (const int*)d_in[4];
    const float* label      = (const float*)d_in[5];
    const float* We1 = (const float*)d_in[6],  *be1 = (const float*)d_in[7];
    const float* We2 = (const float*)d_in[8],  *be2 = (const float*)d_in[9];
    const float *Wc[4], *bc[4], *gw[4], *gb[4], *gm[4];
    for (int i = 0; i < 4; ++i) {
        Wc[i] = (const float*)d_in[10 + i * 5];
        bc[i] = (const float*)d_in[11 + i * 5];
        gw[i] = (const float*)d_in[12 + i * 5];
        gb[i] = (const float*)d_in[13 + i * 5];
        gm[i] = (const float*)d_in[14 + i * 5];
    }
    const float* Wd0 = (const float*)d_in[30], *bd0 = (const float*)d_in[31];
    const float* Wd1 = (const float*)d_in[32], *bd1 = (const float*)d_in[33];
    const float* Wd2 = (const float*)d_in[34], *bd2 = (const float*)d_in[35];
    const float* Wd3 = (const float*)d_in[36], *bd3 = (const float*)d_in[37];

    const int n  = in_sizes[2] / 6;    // 200000
    const int E  = in_sizes[4] / 2;    // 1200000
    const int nl = in_sizes[0] / 19;   // 400
    const int* src = edge_index;
    const int* dst = edge_index + E;

    // Compact workspace (~211.2 MB):
    // [stats 4KB][means 4KB][blocksums 1KB][rowptr n+1][dinv n][esrc E][A n*128][B n*128]
    // transient degi/cursor alias the A region (A first written at encoder-1,
    // strictly after CSR build completes; all kernels stream-ordered).
    auto align256 = [](size_t x) { return (x + 255) & ~(size_t)255; };
    char* w = (char*)d_ws;
    float* stats = (float*)w;                  // 4 layers x 256 floats (sum/sumsq -> a/c)
    float* means = (float*)(w + 4096);
    int* blocksums = (int*)(w + 8192);         // <=256 ints
    size_t off = 8192 + 1024;
    int*   rowptr = (int*)(w + off);   off += align256((size_t)(n + 1) * 4);
    float* dinv   = (float*)(w + off); off += align256((size_t)n * 4);
    int*   esrc   = (int*)(w + off);   off += align256((size_t)E * 4);
    float* A  = (float*)(w + off);             // n*128 floats
    float* B  = A + (size_t)n * 128;           // n*128 floats
    float* A2 = A + (size_t)n * 64;            // second half of A (<=64-wide use)
    float* B2 = B + (size_t)n * 64;            // second half of B
    int*   degi   = (int*)A;                   // transient alias
    int*   cursor = (int*)A2;                  // transient alias

    const float inv_n = 1.0f / (float)n;
    auto cdiv = [](long long a, long long b) { return (int)((a + b - 1) / b); };
    const int nb = cdiv(n, 1024);              // 196 (<=256)

    hipMemsetAsync(stats, 0, 4 * 256 * sizeof(float), stream);
    hipMemsetAsync(degi, 0, (size_t)n * sizeof(int), stream);

    local_means_kernel<<<1, 192, 0, stream>>>(local_x, local_type, means, nl);
    hist_kernel<<<cdiv(E, 256), 256, 0, stream>>>(dst, degi, E);
    scan_part1_kernel<<<nb, 256, 0, stream>>>(degi, blocksums, n);
    scan_part2_kernel<<<1, 256, 0, stream>>>(blocksums, nb);
    scan_part3_kernel<<<nb, 256, 0, stream>>>(degi, blocksums, rowptr, cursor, n, E);
    dinv_kernel<<<cdiv(n, 256), 256, 0, stream>>>(rowptr, dinv, n);
    fill_kernel<<<cdiv(E, 256), 256, 0, stream>>>(src, dst, cursor, esrc, E);
    build_x0_kernel<<<cdiv((long long)n * 32, 256), 256, 0, stream>>>(means, voxel_type, voxel_x, label, B, n);

    const int gmlp = n / 64;
    const int gagg = 2048;

    // encoder: B(32) -> A(128) -> B(128)
    mlp_kernel<32, 128, true, true, false, false><<<gmlp, 256, 0, stream>>>(B, A, We1, be1, nullptr, nullptr);
    mlp_kernel<128, 128, true, true, false, false><<<gmlp, 256, 0, stream>>>(A, B, We2, be2, nullptr, nullptr);

    // conv0: B(128) -> y A(64, dinv-scaled) -> agg A2(64) [+stats]
    mlp_kernel<128, 64, false, false, false, true><<<gmlp, 256, 0, stream>>>(B, A, Wc[0], nullptr, nullptr, dinv);
    gather_agg_kernel<64><<<gagg, 256, 0, stream>>>(A, A2, rowptr, esrc, dinv, bc[0], stats + 0, n);
    gn_finalize_kernel<64><<<1, 64, 0, stream>>>(stats + 0, gw[0], gb[0], gm[0], inv_n);

    // conv1: A2(64,+GN) -> y B(32) -> agg B2(32)
    mlp_kernel<64, 32, false, false, true, true><<<gmlp, 256, 0, stream>>>(A2, B, Wc[1], nullptr, stats + 0, dinv);
    gather_agg_kernel<32><<<gagg, 256, 0, stream>>>(B, B2, rowptr, esrc, dinv, bc[1], stats + 256, n);
    gn_finalize_kernel<32><<<1, 32, 0, stream>>>(stats + 256, gw[1], gb[1], gm[1], inv_n);

    // conv2: B2(32,+GN) -> y A(64) -> agg A2(64)
    mlp_kernel<32, 64, false, false, true, true><<<gmlp, 256, 0, stream>>>(B2, A, Wc[2], nullptr, stats + 256, dinv);
    gather_agg_kernel<64><<<gagg, 256, 0, stream>>>(A, A2, rowptr, esrc, dinv, bc[2], stats + 512, n);
    gn_finalize_kernel<64><<<1, 64, 0, stream>>>(stats + 512, gw[2], gb[2], gm[2], inv_n);

    // conv3: A2(64,+GN) -> y B(128) -> agg A(128)
    mlp_kernel<64, 128, false, false, true, true><<<gmlp, 256, 0, stream>>>(A2, B, Wc[3], nullptr, stats + 512, dinv);
    gather_agg_kernel<128><<<gagg, 256, 0, stream>>>(B, A, rowptr, esrc, dinv, bc[3], stats + 768, n);
    gn_finalize_kernel<128><<<1, 128, 0, stream>>>(stats + 768, gw[3], gb[3], gm[3], inv_n);

    // decoder: A(128,+GN) -> B(64) -> B2(32) -> A(16) -> out
    mlp_kernel<128, 64, true, true, true, false><<<gmlp, 256, 0, stream>>>(A, B, Wd0, bd0, stats + 768, nullptr);
    mlp_kernel<64, 32, true, true, false, false><<<gmlp, 256, 0, stream>>>(B, B2, Wd1, bd1, nullptr, nullptr);
    mlp_kernel<32, 16, true, true, false, false><<<gmlp, 256, 0, stream>>>(B2, A, Wd2, bd2, nullptr, nullptr);
    final_kernel<<<cdiv(n, 256), 256, 0, stream>>>(A, Wd3, bd3, (float*)d_out, n);
}